// Round 11
// baseline (218.249 us; speedup 1.0000x reference)
//
#include <hip/hip_runtime.h>
#include <hip/hip_bf16.h>

#define NN 8
#define TT 192
#define HH 1024
#define DD 128
#define TPP 48
#define EE 16384
#define NEDGE (EE + HH)      // 17408
#define BB (NN * TPP)        // 384
#define NOUT (NN * TT * DD)  // 196608

// ================= K0: deg atomics | twT | CW | inv (198 blocks x 256) =================
__global__ __launch_bounds__(256) void k_pre(
    const int* __restrict__ edges, int* __restrict__ degE,
    const int* __restrict__ node_split, int* __restrict__ inv,
    const float* __restrict__ tcw, const float* __restrict__ tcb,
    const float* __restrict__ W1, float* __restrict__ CW,
    const float* __restrict__ tw, float* __restrict__ twT) {
  int tid = threadIdx.x, bid = blockIdx.x;
  if (bid < 68) {
    int e = bid * 256 + tid;
    if (e < EE) atomicAdd(&degE[edges[2 * e + 1]], 1);
  } else if (bid < 196) {
    int base = (bid - 68) * 512;
#pragma unroll
    for (int u = 0; u < 2; ++u) {
      int ii = base + u * 256 + tid;
      twT[(ii & 511) * DD + (ii >> 9)] = tw[ii];
    }
  } else if (bid == 196) {
    // CW[j][o] = sum_d Conv[j][d]*W1[d][o]; Conv[j<4][d]=tcw[d*4+j], Conv[4][d]=tcb[d]
    for (int j = tid; j < 640; j += 256) {
      int jr = j >> 7, o = j & 127;
      float acc = 0.f;
      if (jr < 4)
        for (int d = 0; d < DD; ++d) acc = fmaf(tcw[d * 4 + jr], W1[d * DD + o], acc);
      else
        for (int d = 0; d < DD; ++d) acc = fmaf(tcb[d], W1[d * DD + o], acc);
      CW[jr * DD + o] = acc;
    }
  } else {
    for (int i = tid; i < 1024; i += 256) inv[node_split[i]] = i;
  }
}

// ================= K1: [0,68) inline-scan + scatter | [68,260) time-emb =================
__global__ __launch_bounds__(256) void k_mid(
    const int* __restrict__ edges, const int* __restrict__ degE,
    const int* __restrict__ inv, int* __restrict__ fill,
    int* __restrict__ csr_src, float* __restrict__ csr_coef,
    float* __restrict__ csum, float* __restrict__ QT, int* __restrict__ row_ptr,
    const int* __restrict__ xm, const float* __restrict__ hour_emb,
    const float* __restrict__ wday_emb, const float* __restrict__ twT,
    const float* __restrict__ twb, float* __restrict__ time_emb,
    float* __restrict__ out) {
  int tid = threadIdx.x, bid = blockIdx.x;
  if (bid < 68) {
    __shared__ int rpL[1025];
    __shared__ int wsumL[4];
    // inline exclusive scan of (deg+1), 4 elems/thread
    int t4 = tid * 4;
    int v0 = degE[t4] + 1, v1 = degE[t4 + 1] + 1;
    int v2 = degE[t4 + 2] + 1, v3 = degE[t4 + 3] + 1;
    int s_ = v0 + v1 + v2 + v3;
    int lane = tid & 63, wid = tid >> 6;
    int inc = s_;
#pragma unroll
    for (int off = 1; off < 64; off <<= 1) {
      int u = __shfl_up(inc, off, 64);
      if (lane >= off) inc += u;
    }
    if (lane == 63) wsumL[wid] = inc;
    __syncthreads();
    int base = 0;
    for (int ww = 0; ww < wid; ++ww) base += wsumL[ww];
    int ex = base + inc - s_;
    rpL[t4] = ex;
    rpL[t4 + 1] = ex + v0;
    rpL[t4 + 2] = ex + v0 + v1;
    rpL[t4 + 3] = ex + v0 + v1 + v2;
    if (tid == 255) rpL[1024] = ex + s_;
    __syncthreads();
    if (bid == 0) {
      for (int i = tid; i < 1025; i += 256) row_ptr[i] = rpL[i];
    }
    // scatter: one edge per thread (68*256 == NEDGE exactly)
    int e = bid * 256 + tid;
    int s, dt;
    if (e < EE) { s = edges[2 * e]; dt = edges[2 * e + 1]; }
    else        { s = dt = e - EE; }
    float cf = rsqrtf((float)(degE[s] + 1) * (float)(degE[dt] + 1));
    int pos = atomicAdd(&fill[dt], 1);
    int at = rpL[dt] + pos;
    csr_src[at] = s;
    csr_coef[at] = cf;
    atomicAdd(&csum[dt], cf);
    atomicAdd(&QT[s * 4 + (inv[dt] >> 8)], cf * (1.0f / 256.0f));
  } else {
    // time embedding for 2 b's per block
    __shared__ float sL[2][512];
    int u = bid - 68;
    int half = tid >> 7, o = tid & 127;
    int b = u * 2 + half;
    int n = b / TPP, tp = b % TPP;
    for (int kk = 0; kk < 4; ++kk) {
      int t = tp * 4 + kk;
      int wd = xm[(n * TT + t) * 2 + 0];
      int hr = xm[(n * TT + t) * 2 + 1];
      sL[half][o * 4 + kk] = hour_emb[hr * DD + o] + wday_emb[wd * DD + o];
    }
    __syncthreads();
    float a0 = twb[o], a1 = 0.f, a2 = 0.f, a3 = 0.f;
    for (int j = 0; j < 512; j += 4) {
      a0 = fmaf(sL[half][j + 0], twT[(j + 0) * DD + o], a0);
      a1 = fmaf(sL[half][j + 1], twT[(j + 1) * DD + o], a1);
      a2 = fmaf(sL[half][j + 2], twT[(j + 2) * DD + o], a2);
      a3 = fmaf(sL[half][j + 3], twT[(j + 3) * DD + o], a3);
    }
    float acc = (a0 + a1) + (a2 + a3);
    time_emb[b * DD + o] = acc;
    size_t bo2 = (size_t)NOUT + ((size_t)n * TT + tp * 4) * DD + o;
    out[bo2] = acc;
    out[bo2 + DD] = acc;
    out[bo2 + 2 * DD] = acc;
    out[bo2 + 3 * DD] = acc;
  }
}

// ================= K2: gather only (384 x 512, LDS 16 KB, 32 waves/CU) =================
__global__ __launch_bounds__(512, 4) void k_gather(
    const float* __restrict__ x, const int* __restrict__ row_ptr,
    const int* __restrict__ csr_src, const float* __restrict__ csr_coef,
    float4* __restrict__ xb4g) {
  __shared__ float x4[1024][4];
  int tid = threadIdx.x;
  int b = blockIdx.x;
  int n = b / TPP, tp = b % TPP;
  const float* xb = x + ((size_t)n * TT + tp * 4) * HH;
#pragma unroll
  for (int i = tid; i < 4096; i += 512) {
    int s = i & 1023, k = i >> 10;  // i = k*1024+s, coalesced read
    x4[s][k] = xb[i];
  }
  __syncthreads();
  for (int u = 0; u < 2; ++u) {
    int h = u * 512 + tid;
    int j0 = row_ptr[h], j1 = row_ptr[h + 1];  // j1 > j0 always (self loop)
    float a0 = 0.f, a1 = 0.f, a2 = 0.f, a3 = 0.f;
    int s = csr_src[j0];
    float cf = csr_coef[j0];
    for (int j = j0; j < j1 - 1; ++j) {
      int s2 = csr_src[j + 1];
      float cf2 = csr_coef[j + 1];
      float4 xv = *(const float4*)&x4[s][0];
      a0 = fmaf(cf, xv.x, a0);
      a1 = fmaf(cf, xv.y, a1);
      a2 = fmaf(cf, xv.z, a2);
      a3 = fmaf(cf, xv.w, a3);
      s = s2;
      cf = cf2;
    }
    float4 xv = *(const float4*)&x4[s][0];
    a0 = fmaf(cf, xv.x, a0);
    a1 = fmaf(cf, xv.y, a1);
    a2 = fmaf(cf, xv.z, a2);
    a3 = fmaf(cf, xv.w, a3);
    xb4g[(size_t)b * 1024 + h] = make_float4(a0, a1, a2, a3);
  }
}

// ================= K3: phase B + W2 + time add (384 x 512, LDS 10 KB) =================
__global__ __launch_bounds__(512, 4) void k_final(
    const float4* __restrict__ xb4g, const float* __restrict__ csum,
    const float4* __restrict__ QT4, const float* __restrict__ CW,
    const float* __restrict__ b1, const float* __restrict__ W2,
    const float* __restrict__ b2, const float* __restrict__ time_emb,
    float* __restrict__ out) {
  __shared__ float yP[4][512];
  __shared__ float yL[512];
  int tid = threadIdx.x;
  int b = blockIdx.x;
  int n = b / TPP, tp = b % TPP;
  int sub = tid >> 7, o = tid & 127;
  float cw0 = CW[o], cw1 = CW[DD + o], cw2 = CW[2 * DD + o];
  float cw3 = CW[3 * DD + o], cw4 = CW[4 * DD + o];
  float b1o = b1[o];
  const float4* xg = xb4g + (size_t)b * 1024;
  float y0 = 0.f, y1 = 0.f, y2 = 0.f, y3 = 0.f;
#pragma unroll 4
  for (int hh = sub * 256; hh < sub * 256 + 256; ++hh) {
    float4 xv = xg[hh];       // wave-broadcast 16B
    float cs = csum[hh];      // broadcast
    float4 q = QT4[hh];       // broadcast
    float t = fmaf(cs, cw4, b1o);
    t = fmaf(xv.x, cw0, t);
    t = fmaf(xv.y, cw1, t);
    t = fmaf(xv.z, cw2, t);
    t = fmaf(xv.w, cw3, t);
    t = fmaxf(t, 0.f);
    y0 = fmaf(q.x, t, y0);
    y1 = fmaf(q.y, t, y1);
    y2 = fmaf(q.z, t, y2);
    y3 = fmaf(q.w, t, y3);
  }
  yP[sub][0 * DD + o] = y0;
  yP[sub][1 * DD + o] = y1;
  yP[sub][2 * DD + o] = y2;
  yP[sub][3 * DD + o] = y3;
  __syncthreads();
  yL[tid] = (yP[0][tid] + yP[1][tid]) + (yP[2][tid] + yP[3][tid]);
  __syncthreads();
  // W2 epilogue: g = sub
  int g = sub;
  float a0 = b2[o], a1 = 0.f, a2 = 0.f, a3 = 0.f;
#pragma unroll 4
  for (int d = 0; d < DD; d += 4) {
    a0 = fmaf(yL[g * DD + d + 0], W2[(d + 0) * DD + o], a0);
    a1 = fmaf(yL[g * DD + d + 1], W2[(d + 1) * DD + o], a1);
    a2 = fmaf(yL[g * DD + d + 2], W2[(d + 2) * DD + o], a2);
    a3 = fmaf(yL[g * DD + d + 3], W2[(d + 3) * DD + o], a3);
  }
  float z = (a0 + a1) + (a2 + a3) + time_emb[b * DD + o];
  out[((size_t)n * TT + tp * 4 + g) * DD + o] = z;
}

extern "C" void kernel_launch(void* const* d_in, const int* in_sizes, int n_in,
                              void* d_out, int out_size, void* d_ws, size_t ws_size,
                              hipStream_t stream) {
  const float* x = (const float*)d_in[0];
  const int* xm = (const int*)d_in[1];
  const int* edges = (const int*)d_in[2];
  const int* node_split = (const int*)d_in[3];
  const float* hour_emb = (const float*)d_in[4];
  const float* wday_emb = (const float*)d_in[5];
  const float* timeconv_w = (const float*)d_in[6];
  const float* timeconv_b = (const float*)d_in[7];
  const float* tcw = (const float*)d_in[8];
  const float* tcb = (const float*)d_in[9];
  const float* W1 = (const float*)d_in[10];
  const float* b1 = (const float*)d_in[11];
  const float* W2 = (const float*)d_in[12];
  const float* b2 = (const float*)d_in[13];
  float* out = (float*)d_out;

  char* w = (char*)d_ws;
  int* degE = (int*)(w + 0);               //    4096 B (memset)
  int* fill = (int*)(w + 4096);            //    4096 B (memset)
  float* csum = (float*)(w + 8192);        //    4096 B (memset)
  float* QT = (float*)(w + 12288);         //   16384 B (memset; 16B aligned)
  int* row_ptr = (int*)(w + 28672);        //    4352 B
  int* inv = (int*)(w + 33024);            //    4096 B
  int* csr_src = (int*)(w + 37120);        //   69632 B
  float* csr_coef = (float*)(w + 106752);  //   69632 B
  float* CW = (float*)(w + 176384);        //    4096 B
  float* twT = (float*)(w + 180480);       //  262144 B
  float* time_emb = (float*)(w + 442624);  //  196608 B
  float4* xb4g = (float4*)(w + 639232);    // 6291456 B (end ~6.93 MB)

  hipMemsetAsync(d_ws, 0, 28672, stream);
  k_pre<<<198, 256, 0, stream>>>(edges, degE, node_split, inv, tcw, tcb, W1, CW,
                                 timeconv_w, twT);
  k_mid<<<260, 256, 0, stream>>>(edges, degE, inv, fill, csr_src, csr_coef, csum, QT,
                                 row_ptr, xm, hour_emb, wday_emb, twT, timeconv_b,
                                 time_emb, out);
  k_gather<<<BB, 512, 0, stream>>>(x, row_ptr, csr_src, csr_coef, xb4g);
  k_final<<<BB, 512, 0, stream>>>(xb4g, csum, (const float4*)QT, CW, b1, W2, b2,
                                  time_emb, out);
}